// Round 2
// baseline (803.634 us; speedup 1.0000x reference)
//
#include <hip/hip_runtime.h>

#define E_TOT 1600000
#define N_AT  50000

typedef unsigned short u16;
typedef __attribute__((ext_vector_type(8))) __bf16 bf16x8;
typedef __attribute__((ext_vector_type(4))) float f32x4;

__device__ __forceinline__ u16 f2bf(float f) {
    unsigned int u = __float_as_uint(f);
    return (u16)((u + 0x7FFFu + ((u >> 16) & 1u)) >> 16);
}
__device__ __forceinline__ float softplus_f(float x) {
    return fmaxf(x, 0.0f) + __logf(1.0f + __expf(-fabsf(x)));
}
__device__ __forceinline__ bf16x8 cvt8(const float* __restrict__ p) {
    f32x4 a = *(const f32x4*)p;
    f32x4 b = *(const f32x4*)(p + 4);
    bf16x8 r;
    r[0] = (__bf16)a[0]; r[1] = (__bf16)a[1]; r[2] = (__bf16)a[2]; r[3] = (__bf16)a[3];
    r[4] = (__bf16)b[0]; r[5] = (__bf16)b[1]; r[6] = (__bf16)b[2]; r[7] = (__bf16)b[3];
    return r;
}

// ---------------------------------------------------------------------------
// K_pre: atom_in_fea fp32 -> bf16 copy (N*64)
// ---------------------------------------------------------------------------
__global__ __launch_bounds__(256) void k_pre(const float* __restrict__ atom,
                                             u16* __restrict__ ab) {
    int i = blockIdx.x * 256 + threadIdx.x;  // grid sized exactly N*64/256
    ab[i] = f2bf(atom[i]);
}

// ---------------------------------------------------------------------------
// K0: swizzle W (row-major fp32 [160][128]) into bf16 B-fragment order:
// wf[((kt*8+ct)*64+lane)*8+j] = W[kt*32 + (lane>>4)*8 + j][ct*16 + (lane&15)]
// ---------------------------------------------------------------------------
__global__ __launch_bounds__(256) void k0_swizzle_w(const float* __restrict__ W,
                                                    u16* __restrict__ wf) {
    int t = blockIdx.x * 256 + threadIdx.x;
    if (t >= 5 * 8 * 64 * 8) return;
    int j = t & 7;
    int lane = (t >> 3) & 63;
    int ct = (t >> 9) & 7;
    int kt = t >> 12;
    int k = kt * 32 + (lane >> 4) * 8 + j;
    int c = ct * 16 + (lane & 15);
    wf[t] = f2bf(W[k * 128 + c]);
}

// ---------------------------------------------------------------------------
// Shared GEMM tile: one wave computes rows [rb, rb+32) x cols [0,128) of
// U = concat(atom[self], atom[nbr], nbr_fea) @ W   (fp32 accumulators)
// A-frag 16x16x32: lane holds A[m=lane&15][k=(lane>>4)*8 + j]
// ---------------------------------------------------------------------------
__device__ __forceinline__ void gemm_tile(const u16* __restrict__ ab,
                                          const float* __restrict__ nbr,
                                          const int* __restrict__ sidx,
                                          const int* __restrict__ nidx,
                                          const u16* __restrict__ wf,
                                          int rb, int lane, f32x4 acc[2][8]) {
    const int mrow = lane & 15, quad = lane >> 4;
    const int r0 = rb + mrow, r1 = r0 + 16;
    const int s0 = sidx[r0], s1 = sidx[r1];
    const int n0 = nidx[r0], n1 = nidx[r1];

    const u16* pa00 = ab + s0 * 64 + quad * 8;
    const u16* pa02 = ab + n0 * 64 + quad * 8;
    const u16* pa10 = ab + s1 * 64 + quad * 8;
    const u16* pa12 = ab + n1 * 64 + quad * 8;

    bf16x8 A0[5], A1[5];
    A0[0] = *(const bf16x8*)pa00;        A1[0] = *(const bf16x8*)pa10;
    A0[1] = *(const bf16x8*)(pa00 + 32); A1[1] = *(const bf16x8*)(pa10 + 32);
    A0[2] = *(const bf16x8*)pa02;        A1[2] = *(const bf16x8*)pa12;
    A0[3] = *(const bf16x8*)(pa02 + 32); A1[3] = *(const bf16x8*)(pa12 + 32);
    A0[4] = cvt8(nbr + r0 * 32 + quad * 8);
    A1[4] = cvt8(nbr + r1 * 32 + quad * 8);

#pragma unroll
    for (int kt = 0; kt < 5; kt++) {
#pragma unroll
        for (int ct = 0; ct < 8; ct++) {
            bf16x8 b = *(const bf16x8*)(wf + ((kt * 8 + ct) * 64 + lane) * 8);
            acc[0][ct] = __builtin_amdgcn_mfma_f32_16x16x32_bf16(A0[kt], b, acc[0][ct], 0, 0, 0);
            acc[1][ct] = __builtin_amdgcn_mfma_f32_16x16x32_bf16(A1[kt], b, acc[1][ct], 0, 0, 0);
        }
    }
}

// ---------------------------------------------------------------------------
// K1: GEMM pass 1 -> per-block per-column sum / sumsq partials
// grid = 12500 blocks x 256 thr, 128 edges per block
// ---------------------------------------------------------------------------
__global__ __launch_bounds__(256) void k1_stats(const u16* __restrict__ ab,
                                                const float* __restrict__ nbr,
                                                const int* __restrict__ sidx,
                                                const int* __restrict__ nidx,
                                                const u16* __restrict__ wf,
                                                float* __restrict__ statsbuf) {
    const int tx = threadIdx.x, lane = tx & 63, w = tx >> 6;
    const int rb = blockIdx.x * 128 + w * 32;

    f32x4 acc[2][8];
#pragma unroll
    for (int i = 0; i < 2; i++)
#pragma unroll
        for (int j = 0; j < 8; j++) { f32x4 z = {0.f, 0.f, 0.f, 0.f}; acc[i][j] = z; }

    gemm_tile(ab, nbr, sidx, nidx, wf, rb, lane, acc);

    __shared__ float bs[256];  // [0..127] = sum, [128..255] = sumsq
    bs[tx] = 0.0f;
    __syncthreads();

    const int mrow = lane & 15, quad = lane >> 4;
#pragma unroll
    for (int ct = 0; ct < 8; ct++) {
        float s = 0.f, q = 0.f;
#pragma unroll
        for (int rf = 0; rf < 2; rf++)
#pragma unroll
            for (int rg = 0; rg < 4; rg++) {
                float v = acc[rf][ct][rg];
                s += v; q += v * v;
            }
        // C/D col = lane&15; sum over the 4 quads (lanes 16 apart share a col)
        s += __shfl_xor(s, 16, 64); s += __shfl_xor(s, 32, 64);
        q += __shfl_xor(q, 16, 64); q += __shfl_xor(q, 32, 64);
        if (quad == 0) {
            atomicAdd(&bs[ct * 16 + mrow], s);
            atomicAdd(&bs[128 + ct * 16 + mrow], q);
        }
    }
    __syncthreads();
    statsbuf[blockIdx.x * 256 + tx] = bs[tx];
}

// ---------------------------------------------------------------------------
// K2: reduce 12500 x 256 partials -> sums1[256]
// ---------------------------------------------------------------------------
__global__ __launch_bounds__(256) void k2_reduce(const float* __restrict__ statsbuf,
                                                 float* __restrict__ sums1) {
    const int tx = threadIdx.x;
    float s = 0.f;
    for (int b = blockIdx.x; b < 12500; b += gridDim.x)
        s += statsbuf[b * 256 + tx];
    atomicAdd(&sums1[tx], s);
}

// ---------------------------------------------------------------------------
// K3: GEMM pass 2 + BN1 + sigmoid*softplus + run-based segment sum (atomics)
// ---------------------------------------------------------------------------
__global__ __launch_bounds__(256) void k3_msg(const u16* __restrict__ ab,
                                              const float* __restrict__ nbr,
                                              const int* __restrict__ sidx,
                                              const int* __restrict__ nidx,
                                              const u16* __restrict__ wf,
                                              const float* __restrict__ sums1,
                                              const float* __restrict__ g1,
                                              const float* __restrict__ b1,
                                              float* __restrict__ ns) {
    const int tx = threadIdx.x, lane = tx & 63, w = tx >> 6;
    const int blk = blockIdx.x;
    const int rb = blk * 128 + w * 32;

    f32x4 acc[2][8];
#pragma unroll
    for (int i = 0; i < 2; i++)
#pragma unroll
        for (int j = 0; j < 8; j++) { f32x4 z = {0.f, 0.f, 0.f, 0.f}; acc[i][j] = z; }

    gemm_tile(ab, nbr, sidx, nidx, wf, rb, lane, acc);

    __shared__ float msg[128][66];  // stride 66 -> 2-way (free) bank aliasing
    const int mrow = lane & 15, quad = lane >> 4;
    const float invE = 1.0f / (float)E_TOT;

#pragma unroll
    for (int ct = 0; ct < 4; ct++) {
        const int cf = ct * 16 + mrow;  // filter col (0..63) == message feature
        const int cc = cf + 64;         // core col
        float mf = sums1[cf] * invE;
        float vf = sums1[128 + cf] * invE - mf * mf;
        float af = g1[cf] * rsqrtf(vf + 1e-5f);
        float kf = b1[cf] - af * mf;
        float mc = sums1[cc] * invE;
        float vc = sums1[128 + cc] * invE - mc * mc;
        float ac = g1[cc] * rsqrtf(vc + 1e-5f);
        float kc = b1[cc] - ac * mc;
#pragma unroll
        for (int rf = 0; rf < 2; rf++)
#pragma unroll
            for (int rg = 0; rg < 4; rg++) {
                // C/D layout: edge row = quad*4+rg (+16 per rf), feature col = mrow
                float xf = af * acc[rf][ct][rg] + kf;
                float xc = ac * acc[rf][ct + 4][rg] + kc;
                float sg = 1.0f / (1.0f + __expf(-xf));
                msg[w * 32 + rf * 16 + quad * 4 + rg][cf] = sg * softplus_f(xc);
            }
    }
    __syncthreads();

    // wave w scans its 32 sorted edges; lane = feature column (0..63)
    const int ebase = blk * 128 + w * 32;
    float accum = 0.f;
    int cur = sidx[ebase];
    for (int i = 0; i < 32; i++) {
        int idx = sidx[ebase + i];
        if (idx != cur) {
            atomicAdd(&ns[cur * 64 + lane], accum);
            accum = 0.f;
            cur = idx;
        }
        accum += msg[w * 32 + i][lane];
    }
    atomicAdd(&ns[cur * 64 + lane], accum);
}

// ---------------------------------------------------------------------------
// K4: BN2 stats over nbr_sumed (N x 64 fp32) -> sums2[128]
// ---------------------------------------------------------------------------
__global__ __launch_bounds__(256) void k4_bn2stats(const float* __restrict__ ns,
                                                   float* __restrict__ sums2) {
    const int tx = threadIdx.x;
    const int col = tx & 63, rg = tx >> 6;
    float s = 0.f, q = 0.f;
    for (int r = blockIdx.x * 4 + rg; r < N_AT; r += 256 * 4) {
        float v = ns[r * 64 + col];
        s += v; q += v * v;
    }
    atomicAdd(&sums2[col], s);
    atomicAdd(&sums2[64 + col], q);
}

// ---------------------------------------------------------------------------
// K5: out = softplus(atom + BN2(nbr_sumed))   (fp32 out)
// ---------------------------------------------------------------------------
__global__ __launch_bounds__(256) void k5_final(const float* __restrict__ atom,
                                                const float* __restrict__ ns,
                                                const float* __restrict__ sums2,
                                                const float* __restrict__ g2,
                                                const float* __restrict__ b2,
                                                float* __restrict__ out) {
    const int i = blockIdx.x * 256 + threadIdx.x;  // grid sized exactly N*64/256
    const int col = i & 63;
    const float invN = 1.0f / (float)N_AT;
    float mean = sums2[col] * invN;
    float var = sums2[64 + col] * invN - mean * mean;
    float a2 = g2[col] * rsqrtf(var + 1e-5f);
    float c2 = b2[col] - a2 * mean;
    float x = atom[i] + a2 * ns[i] + c2;
    out[i] = softplus_f(x);
}

// ---------------------------------------------------------------------------
// Workspace layout (bytes), total ~32.1 MB:
//   [0, 12.8M)     statsbuf  (12500*256 fp32)  -- fully written by K1
//   [+0, 1K)       sums1     (256 fp32)        -- memset 0
//   [+, 12.8M)     nbr_sumed (50000*64 fp32)   -- memset 0
//   [+, 512)       sums2     (128 fp32)        -- memset 0
//   [+, 40K)       wf        (20480 bf16)      -- fully written by K0
//   [+, 6.4M)      ab        (N*64 bf16)       -- fully written by K_pre
// ---------------------------------------------------------------------------
extern "C" void kernel_launch(void* const* d_in, const int* in_sizes, int n_in,
                              void* d_out, int out_size, void* d_ws, size_t ws_size,
                              hipStream_t stream) {
    const float* atom = (const float*)d_in[0];
    const float* nbr  = (const float*)d_in[1];
    const int* sidx   = (const int*)d_in[2];
    const int* nidx   = (const int*)d_in[3];
    const float* W    = (const float*)d_in[4];
    // d_in[5] = b : cancels exactly under training-mode BN1 -> unused
    const float* g1   = (const float*)d_in[6];
    const float* b1   = (const float*)d_in[7];
    const float* g2   = (const float*)d_in[8];
    const float* b2   = (const float*)d_in[9];
    float* out = (float*)d_out;

    char* ws = (char*)d_ws;
    const size_t STAT1_OFF = 0;
    const size_t SUM1_OFF  = STAT1_OFF + (size_t)12500 * 256 * 4;  // 12,800,000
    const size_t NS_OFF    = SUM1_OFF + 1024;
    const size_t SUM2_OFF  = NS_OFF + (size_t)N_AT * 64 * 4;       // +12,800,000
    const size_t WF_OFF    = SUM2_OFF + 512;
    const size_t AB_OFF    = WF_OFF + 40960;

    float* statsbuf = (float*)(ws + STAT1_OFF);
    float* sums1    = (float*)(ws + SUM1_OFF);
    float* nsumed   = (float*)(ws + NS_OFF);
    float* sums2    = (float*)(ws + SUM2_OFF);
    u16*   wf       = (u16*)(ws + WF_OFF);
    u16*   ab       = (u16*)(ws + AB_OFF);

    // zero sums1 + nbr_sumed + sums2 (contiguous region)
    hipMemsetAsync(ws + SUM1_OFF, 0, 1024 + (size_t)N_AT * 64 * 4 + 512, stream);

    k_pre<<<(N_AT * 64) / 256, 256, 0, stream>>>(atom, ab);
    k0_swizzle_w<<<80, 256, 0, stream>>>(W, wf);
    k1_stats<<<E_TOT / 128, 256, 0, stream>>>(ab, nbr, sidx, nidx, wf, statsbuf);
    k2_reduce<<<64, 256, 0, stream>>>(statsbuf, sums1);
    k3_msg<<<E_TOT / 128, 256, 0, stream>>>(ab, nbr, sidx, nidx, wf, sums1, g1, b1, nsumed);
    k4_bn2stats<<<256, 256, 0, stream>>>(nsumed, sums2);
    k5_final<<<(N_AT * 64) / 256, 256, 0, stream>>>(atom, nsumed, sums2, g2, b2, out);
}

// Round 3
// 741.567 us; speedup vs baseline: 1.0837x; 1.0837x over previous
//
#include <hip/hip_runtime.h>

#define E_TOT 1600000
#define N_AT  50000

typedef unsigned short u16;
typedef __attribute__((ext_vector_type(8))) __bf16 bf16x8;
typedef __attribute__((ext_vector_type(4))) float f32x4;

// Workspace layout (byte offsets), all 16B-aligned:
//   [0,       1024)   sums1 (256 f32)  -- zeroed by k_setup
//   [1024,    1536)   sums2 (128 f32)  -- zeroed by k_setup
//   [2048,   43008)   wf    (20480 bf16, B-fragment order) -- written by k_setup
//   [43008, +12.8M)   ns    (N*64 f32) -- zeroed by k_setup
//   [+,      +6.4M)   ab    (N*64 bf16) -- written by k_setup
//   [+,    +102.4M)   nbrb  (E*32 bf16) -- written by k1 (CVT path only)
#define SUM1_OFF 0
#define SUM2_OFF 1024
#define WF_OFF   2048
#define NS_OFF   43008
#define AB_OFF   12843008
#define NBRB_OFF 19243008
#define WS_FULL  121643008ULL

__device__ __forceinline__ u16 f2bf(float f) {
    unsigned int u = __float_as_uint(f);
    return (u16)((u + 0x7FFFu + ((u >> 16) & 1u)) >> 16);
}
__device__ __forceinline__ float softplus_f(float x) {
    return fmaxf(x, 0.0f) + __logf(1.0f + __expf(-fabsf(x)));
}
__device__ __forceinline__ bf16x8 cvt8v(f32x4 a, f32x4 b) {
    bf16x8 r;
    r[0] = (__bf16)a[0]; r[1] = (__bf16)a[1]; r[2] = (__bf16)a[2]; r[3] = (__bf16)a[3];
    r[4] = (__bf16)b[0]; r[5] = (__bf16)b[1]; r[6] = (__bf16)b[2]; r[7] = (__bf16)b[3];
    return r;
}

// ---------------------------------------------------------------------------
// k_setup: zero sums1/sums2/ns + cvt atom->ab + swizzle W->wf (one kernel,
// replaces memset + k_pre + k0; runs fresh every call since ws is re-poisoned)
// ---------------------------------------------------------------------------
__global__ __launch_bounds__(256) void k_setup(const float* __restrict__ atom,
                                               const float* __restrict__ W,
                                               char* __restrict__ ws) {
    u16* wf   = (u16*)(ws + WF_OFF);
    float* ns = (float*)(ws + NS_OFF);
    u16* ab   = (u16*)(ws + AB_OFF);
    const int tid = blockIdx.x * 256 + threadIdx.x;
    const int gsz = gridDim.x * 256;

    for (int i = tid; i < 512; i += gsz) ((float*)ws)[i] = 0.0f;  // sums1+sums2

    f32x4 z = {0.f, 0.f, 0.f, 0.f};
    for (int i = tid; i < N_AT * 64 / 4; i += gsz) ((f32x4*)ns)[i] = z;

    for (int i = tid; i < N_AT * 64 / 4; i += gsz) {
        f32x4 v = ((const f32x4*)atom)[i];
        u16 r[4];
        r[0] = f2bf(v[0]); r[1] = f2bf(v[1]); r[2] = f2bf(v[2]); r[3] = f2bf(v[3]);
        *(unsigned long long*)(ab + i * 4) =
            (unsigned long long)r[0] | ((unsigned long long)r[1] << 16) |
            ((unsigned long long)r[2] << 32) | ((unsigned long long)r[3] << 48);
    }

    for (int t = tid; t < 20480; t += gsz) {
        int j = t & 7, l2 = (t >> 3) & 63, ct = (t >> 9) & 7, kt = t >> 12;
        int k = kt * 32 + (l2 >> 4) * 8 + j;
        int c = ct * 16 + (l2 & 15);
        wf[t] = f2bf(W[k * 128 + c]);
    }
}

// ---------------------------------------------------------------------------
// k1: GEMM pass 1 (stats). Block = 256 thr = 4 waves, 256 rows/block,
// 2 interleaved 32-row tiles per wave. B staged in LDS once per block.
// Also converts nbr_fea -> bf16 nbrb for k3 (CVT path).
// ---------------------------------------------------------------------------
template<bool CVT>
__global__ __launch_bounds__(256, 2) void k1_stats(const u16* __restrict__ ab,
                                                   const float* __restrict__ nbr,
                                                   u16* __restrict__ nbrb,
                                                   const int* __restrict__ sidx,
                                                   const int* __restrict__ nidx,
                                                   const u16* __restrict__ wf,
                                                   float* __restrict__ sums1) {
    __shared__ u16 bsm[20480];   // 40 KB: W in fragment order
    __shared__ float bs[256];
    const int tx = threadIdx.x, lane = tx & 63, w = tx >> 6;
    const int mrow = lane & 15, quad = lane >> 4;

#pragma unroll
    for (int i = 0; i < 10; i++) {
        int idx = (i * 256 + tx) * 8;             // coalesced 1KB per wave-instr
        *(bf16x8*)&bsm[idx] = *(const bf16x8*)&wf[idx];
    }
    bs[tx] = 0.0f;
    __syncthreads();

    const int RB = blockIdx.x * 256;
    int rr[2][2];
    const u16* ps[2][2];
    const u16* pn[2][2];
#pragma unroll
    for (int t = 0; t < 2; t++)
#pragma unroll
        for (int rf = 0; rf < 2; rf++) {
            int r = RB + t * 128 + w * 32 + rf * 16 + mrow;
            rr[t][rf] = r;
            ps[t][rf] = ab + sidx[r] * 64 + quad * 8;
            pn[t][rf] = ab + nidx[r] * 64 + quad * 8;
        }

    f32x4 acc[2][2][8];
#pragma unroll
    for (int t = 0; t < 2; t++)
#pragma unroll
        for (int rf = 0; rf < 2; rf++)
#pragma unroll
            for (int ct = 0; ct < 8; ct++) {
                f32x4 z = {0.f, 0.f, 0.f, 0.f};
                acc[t][rf][ct] = z;
            }

#pragma unroll
    for (int kt = 0; kt < 5; kt++) {
        bf16x8 a[2][2];
#pragma unroll
        for (int t = 0; t < 2; t++)
#pragma unroll
            for (int rf = 0; rf < 2; rf++) {
                if (kt < 2)      a[t][rf] = *(const bf16x8*)(ps[t][rf] + kt * 32);
                else if (kt < 4) a[t][rf] = *(const bf16x8*)(pn[t][rf] + (kt - 2) * 32);
                else {
                    const float* p = nbr + rr[t][rf] * 32 + quad * 8;
                    bf16x8 av = cvt8v(*(const f32x4*)p, *(const f32x4*)(p + 4));
                    if (CVT) *(bf16x8*)(nbrb + rr[t][rf] * 32 + quad * 8) = av;
                    a[t][rf] = av;
                }
            }
#pragma unroll
        for (int ct = 0; ct < 8; ct++) {
            bf16x8 b = *(const bf16x8*)&bsm[((kt * 8 + ct) * 64 + lane) * 8];
            acc[0][0][ct] = __builtin_amdgcn_mfma_f32_16x16x32_bf16(a[0][0], b, acc[0][0][ct], 0, 0, 0);
            acc[0][1][ct] = __builtin_amdgcn_mfma_f32_16x16x32_bf16(a[0][1], b, acc[0][1][ct], 0, 0, 0);
            acc[1][0][ct] = __builtin_amdgcn_mfma_f32_16x16x32_bf16(a[1][0], b, acc[1][0][ct], 0, 0, 0);
            acc[1][1][ct] = __builtin_amdgcn_mfma_f32_16x16x32_bf16(a[1][1], b, acc[1][1][ct], 0, 0, 0);
        }
    }

#pragma unroll
    for (int ct = 0; ct < 8; ct++) {
        float s = 0.f, q = 0.f;
#pragma unroll
        for (int t = 0; t < 2; t++)
#pragma unroll
            for (int rf = 0; rf < 2; rf++)
#pragma unroll
                for (int rg = 0; rg < 4; rg++) {
                    float v = acc[t][rf][ct][rg];
                    s += v; q += v * v;
                }
        s += __shfl_xor(s, 16, 64); s += __shfl_xor(s, 32, 64);
        q += __shfl_xor(q, 16, 64); q += __shfl_xor(q, 32, 64);
        if (quad == 0) {
            atomicAdd(&bs[ct * 16 + mrow], s);
            atomicAdd(&bs[128 + ct * 16 + mrow], q);
        }
    }
    __syncthreads();
    atomicAdd(&sums1[tx], bs[tx]);   // fused k2: one global atomic per thread
}

// ---------------------------------------------------------------------------
// k3: GEMM pass 2 + BN1 + sigmoid*softplus + segment-sum. Same GEMM core.
// Epilogue: per 16-row half-tile -> per-wave LDS transpose (no barrier
// needed: same-wave write/read) -> register scan -> coalesced atomics.
// ---------------------------------------------------------------------------
template<bool NB>
__global__ __launch_bounds__(256, 2) void k3_msg(const u16* __restrict__ ab,
                                                 const float* __restrict__ nbr,
                                                 const u16* __restrict__ nbrb,
                                                 const int* __restrict__ sidx,
                                                 const int* __restrict__ nidx,
                                                 const u16* __restrict__ wf,
                                                 const float* __restrict__ sums1,
                                                 const float* __restrict__ g1,
                                                 const float* __restrict__ b1,
                                                 float* __restrict__ ns) {
    __shared__ u16 bsm[20480];        // 40 KB
    __shared__ float msg[4][16 * 66]; // 16.5 KB: per-wave 16-row transpose buf
    const int tx = threadIdx.x, lane = tx & 63, w = tx >> 6;
    const int mrow = lane & 15, quad = lane >> 4;

#pragma unroll
    for (int i = 0; i < 10; i++) {
        int idx = (i * 256 + tx) * 8;
        *(bf16x8*)&bsm[idx] = *(const bf16x8*)&wf[idx];
    }
    __syncthreads();

    // BN1 affine constants (bias b cancels under training-mode BN)
    const float invE = 1.0f / (float)E_TOT;
    float af[4], kf[4], ac[4], kc[4];
#pragma unroll
    for (int ct = 0; ct < 4; ct++) {
        int cf = ct * 16 + mrow, cc = cf + 64;
        float mf = sums1[cf] * invE;
        float vf = sums1[128 + cf] * invE - mf * mf;
        af[ct] = g1[cf] * rsqrtf(vf + 1e-5f);
        kf[ct] = b1[cf] - af[ct] * mf;
        float mc = sums1[cc] * invE;
        float vc = sums1[128 + cc] * invE - mc * mc;
        ac[ct] = g1[cc] * rsqrtf(vc + 1e-5f);
        kc[ct] = b1[cc] - ac[ct] * mc;
    }

    const int RB = blockIdx.x * 256;
    int rr[2][2];
    const u16* ps[2][2];
    const u16* pn[2][2];
#pragma unroll
    for (int t = 0; t < 2; t++)
#pragma unroll
        for (int rf = 0; rf < 2; rf++) {
            int r = RB + t * 128 + w * 32 + rf * 16 + mrow;
            rr[t][rf] = r;
            ps[t][rf] = ab + sidx[r] * 64 + quad * 8;
            pn[t][rf] = ab + nidx[r] * 64 + quad * 8;
        }

    f32x4 acc[2][2][8];
#pragma unroll
    for (int t = 0; t < 2; t++)
#pragma unroll
        for (int rf = 0; rf < 2; rf++)
#pragma unroll
            for (int ct = 0; ct < 8; ct++) {
                f32x4 z = {0.f, 0.f, 0.f, 0.f};
                acc[t][rf][ct] = z;
            }

#pragma unroll
    for (int kt = 0; kt < 5; kt++) {
        bf16x8 a[2][2];
#pragma unroll
        for (int t = 0; t < 2; t++)
#pragma unroll
            for (int rf = 0; rf < 2; rf++) {
                if (kt < 2)      a[t][rf] = *(const bf16x8*)(ps[t][rf] + kt * 32);
                else if (kt < 4) a[t][rf] = *(const bf16x8*)(pn[t][rf] + (kt - 2) * 32);
                else {
                    if (NB) a[t][rf] = *(const bf16x8*)(nbrb + rr[t][rf] * 32 + quad * 8);
                    else {
                        const float* p = nbr + rr[t][rf] * 32 + quad * 8;
                        a[t][rf] = cvt8v(*(const f32x4*)p, *(const f32x4*)(p + 4));
                    }
                }
            }
#pragma unroll
        for (int ct = 0; ct < 8; ct++) {
            bf16x8 b = *(const bf16x8*)&bsm[((kt * 8 + ct) * 64 + lane) * 8];
            acc[0][0][ct] = __builtin_amdgcn_mfma_f32_16x16x32_bf16(a[0][0], b, acc[0][0][ct], 0, 0, 0);
            acc[0][1][ct] = __builtin_amdgcn_mfma_f32_16x16x32_bf16(a[0][1], b, acc[0][1][ct], 0, 0, 0);
            acc[1][0][ct] = __builtin_amdgcn_mfma_f32_16x16x32_bf16(a[1][0], b, acc[1][0][ct], 0, 0, 0);
            acc[1][1][ct] = __builtin_amdgcn_mfma_f32_16x16x32_bf16(a[1][1], b, acc[1][1][ct], 0, 0, 0);
        }
    }

    // Epilogue: per 16-row half-tile (boundary flush at the 16-row edge is
    // just an extra atomic -- correctness unaffected, keeps LDS small)
    float* mw = msg[w];
#pragma unroll
    for (int t = 0; t < 2; t++) {
#pragma unroll
        for (int rf = 0; rf < 2; rf++) {
#pragma unroll
            for (int ct = 0; ct < 4; ct++) {
#pragma unroll
                for (int rg = 0; rg < 4; rg++) {
                    // C/D layout: row = quad*4+rg, col = mrow (+16*ct)
                    float xf = af[ct] * acc[t][rf][ct][rg] + kf[ct];
                    float xc = ac[ct] * acc[t][rf][ct + 4][rg] + kc[ct];
                    float sg = 1.0f / (1.0f + __expf(-xf));
                    mw[(quad * 4 + rg) * 66 + ct * 16 + mrow] = sg * softplus_f(xc);
                }
            }
            const int ebase = RB + t * 128 + w * 32 + rf * 16;
            float mv[16];
#pragma unroll
            for (int i = 0; i < 16; i++) mv[i] = mw[i * 66 + lane];
            float accum = 0.f;
            int cur = sidx[ebase];
#pragma unroll
            for (int i = 0; i < 16; i++) {
                int idx = sidx[ebase + i];   // wave-uniform -> scalar loads
                if (idx != cur) {
                    atomicAdd(&ns[cur * 64 + lane], accum);
                    accum = 0.f;
                    cur = idx;
                }
                accum += mv[i];
            }
            atomicAdd(&ns[cur * 64 + lane], accum);
        }
    }
}

// ---------------------------------------------------------------------------
// k4: BN2 stats over nbr_sumed (N x 64 f32) -> sums2[128]
// ---------------------------------------------------------------------------
__global__ __launch_bounds__(256) void k4_bn2stats(const float* __restrict__ ns,
                                                   float* __restrict__ sums2) {
    const int tx = threadIdx.x;
    const int col = tx & 63, rg = tx >> 6;
    float s = 0.f, q = 0.f;
    for (int r = blockIdx.x * 4 + rg; r < N_AT; r += 256 * 4) {
        float v = ns[r * 64 + col];
        s += v; q += v * v;
    }
    atomicAdd(&sums2[col], s);
    atomicAdd(&sums2[64 + col], q);
}

// ---------------------------------------------------------------------------
// k5: out = softplus(atom + BN2(nbr_sumed))
// ---------------------------------------------------------------------------
__global__ __launch_bounds__(256) void k5_final(const float* __restrict__ atom,
                                                const float* __restrict__ ns,
                                                const float* __restrict__ sums2,
                                                const float* __restrict__ g2,
                                                const float* __restrict__ b2,
                                                float* __restrict__ out) {
    const int i = blockIdx.x * 256 + threadIdx.x;  // grid covers N*64 exactly
    const int col = i & 63;
    const float invN = 1.0f / (float)N_AT;
    float mean = sums2[col] * invN;
    float var = sums2[64 + col] * invN - mean * mean;
    float a2 = g2[col] * rsqrtf(var + 1e-5f);
    float c2 = b2[col] - a2 * mean;
    out[i] = softplus_f(atom[i] + a2 * ns[i] + c2);
}

extern "C" void kernel_launch(void* const* d_in, const int* in_sizes, int n_in,
                              void* d_out, int out_size, void* d_ws, size_t ws_size,
                              hipStream_t stream) {
    const float* atom = (const float*)d_in[0];
    const float* nbr  = (const float*)d_in[1];
    const int* sidx   = (const int*)d_in[2];
    const int* nidx   = (const int*)d_in[3];
    const float* W    = (const float*)d_in[4];
    // d_in[5] = b : cancels exactly under training-mode BN1 -> unused
    const float* g1   = (const float*)d_in[6];
    const float* b1   = (const float*)d_in[7];
    const float* g2   = (const float*)d_in[8];
    const float* b2   = (const float*)d_in[9];
    float* out = (float*)d_out;

    char* ws = (char*)d_ws;
    float* sums1 = (float*)(ws + SUM1_OFF);
    float* sums2 = (float*)(ws + SUM2_OFF);
    u16*   wf    = (u16*)(ws + WF_OFF);
    float* nsum  = (float*)(ws + NS_OFF);
    u16*   ab    = (u16*)(ws + AB_OFF);
    u16*   nbrb  = (u16*)(ws + NBRB_OFF);

    const bool big = ws_size >= (size_t)WS_FULL;  // deterministic per process

    k_setup<<<1024, 256, 0, stream>>>(atom, W, ws);
    if (big) {
        k1_stats<true><<<E_TOT / 256, 256, 0, stream>>>(ab, nbr, nbrb, sidx, nidx, wf, sums1);
        k3_msg<true><<<E_TOT / 256, 256, 0, stream>>>(ab, nbr, nbrb, sidx, nidx, wf, sums1, g1, b1, nsum);
    } else {
        k1_stats<false><<<E_TOT / 256, 256, 0, stream>>>(ab, nbr, nbrb, sidx, nidx, wf, sums1);
        k3_msg<false><<<E_TOT / 256, 256, 0, stream>>>(ab, nbr, nbrb, sidx, nidx, wf, sums1, g1, b1, nsum);
    }
    k4_bn2stats<<<256, 256, 0, stream>>>(nsum, sums2);
    k5_final<<<(N_AT * 64) / 256, 256, 0, stream>>>(atom, nsum, sums2, g2, b2, out);
}